// Round 1
// baseline (2744.018 us; speedup 1.0000x reference)
//
#include <hip/hip_runtime.h>
#include <math.h>

#define NN 200000
#define NE 3200000
#define IN_DIM 16
#define EMB 8

// ---------------- kernel 1: node init ----------------
// p = x @ W1l^T   (what gets gathered/scattered)
// t = x @ W1r^T + b1  (the "self" term)
// agg = 0, cnt = 0
__global__ __launch_bounds__(256) void k_init(
    const float* __restrict__ x,
    const float* __restrict__ W1l,   // [8][16]
    const float* __restrict__ W1r,   // [8][16]
    const float* __restrict__ b1,    // [8]
    float* __restrict__ p, float* __restrict__ t,
    float* __restrict__ agg, float* __restrict__ cnt)
{
    __shared__ float sWl[EMB * IN_DIM];
    __shared__ float sWr[EMB * IN_DIM];
    __shared__ float sb[EMB];
    int tid = threadIdx.x;
    if (tid < EMB * IN_DIM) { sWl[tid] = W1l[tid]; sWr[tid] = W1r[tid]; }
    if (tid < EMB) sb[tid] = b1[tid];
    __syncthreads();

    int i = blockIdx.x * blockDim.x + tid;
    if (i >= NN) return;

    float xi[IN_DIM];
    const float4* xp = (const float4*)(x + (size_t)i * IN_DIM);
    #pragma unroll
    for (int q = 0; q < 4; ++q) {
        float4 v = xp[q];
        xi[4*q+0] = v.x; xi[4*q+1] = v.y; xi[4*q+2] = v.z; xi[4*q+3] = v.w;
    }

    float pe[EMB], te[EMB];
    #pragma unroll
    for (int e = 0; e < EMB; ++e) {
        float sp = 0.f, st = sb[e];
        #pragma unroll
        for (int k = 0; k < IN_DIM; ++k) {
            sp = fmaf(xi[k], sWl[e * IN_DIM + k], sp);
            st = fmaf(xi[k], sWr[e * IN_DIM + k], st);
        }
        pe[e] = sp; te[e] = st;
    }

    float4* pp = (float4*)(p + (size_t)i * EMB);
    float4* tp = (float4*)(t + (size_t)i * EMB);
    float4* ap = (float4*)(agg + (size_t)i * EMB);
    pp[0] = make_float4(pe[0], pe[1], pe[2], pe[3]);
    pp[1] = make_float4(pe[4], pe[5], pe[6], pe[7]);
    tp[0] = make_float4(te[0], te[1], te[2], te[3]);
    tp[1] = make_float4(te[4], te[5], te[6], te[7]);
    ap[0] = make_float4(0.f, 0.f, 0.f, 0.f);
    ap[1] = make_float4(0.f, 0.f, 0.f, 0.f);
    cnt[i] = 0.f;
}

// ---------------- kernel 2/4: edge scatter ----------------
template<bool COUNT>
__global__ __launch_bounds__(256) void k_scatter(
    const int* __restrict__ src,
    const int* __restrict__ dst,
    const float* __restrict__ w,
    const float* __restrict__ p,
    float* __restrict__ agg, float* __restrict__ cnt)
{
    int e = blockIdx.x * blockDim.x + threadIdx.x;
    if (e >= NE) return;
    int s = src[e];
    int d = dst[e];
    float we = w[e];
    const float4* ps = (const float4*)(p + (size_t)s * EMB);
    float4 v0 = ps[0], v1 = ps[1];
    float* ad = agg + (size_t)d * EMB;
    atomicAdd(ad + 0, v0.x * we);
    atomicAdd(ad + 1, v0.y * we);
    atomicAdd(ad + 2, v0.z * we);
    atomicAdd(ad + 3, v0.w * we);
    atomicAdd(ad + 4, v1.x * we);
    atomicAdd(ad + 5, v1.y * we);
    atomicAdd(ad + 6, v1.z * we);
    atomicAdd(ad + 7, v1.w * we);
    if (COUNT) atomicAdd(cnt + d, 1.0f);
}

// ---------------- kernel 3: layer-1 finalize + layer-2 prep ----------------
// h = relu(agg/max(cnt,1) + t); p <- h @ W3l^T; t <- h @ W3r^T + b3; agg <- 0
__global__ __launch_bounds__(256) void k_mid(
    const float* __restrict__ W3l,   // [8][8]
    const float* __restrict__ W3r,   // [8][8]
    const float* __restrict__ b3,    // [8]
    float* __restrict__ p, float* __restrict__ t,
    float* __restrict__ agg, const float* __restrict__ cnt)
{
    __shared__ float sWl[EMB * EMB];
    __shared__ float sWr[EMB * EMB];
    __shared__ float sb[EMB];
    int tid = threadIdx.x;
    if (tid < EMB * EMB) { sWl[tid] = W3l[tid]; sWr[tid] = W3r[tid]; }
    if (tid < EMB) sb[tid] = b3[tid];
    __syncthreads();

    int i = blockIdx.x * blockDim.x + tid;
    if (i >= NN) return;

    float4* ap = (float4*)(agg + (size_t)i * EMB);
    float4* tp = (float4*)(t + (size_t)i * EMB);
    float4* pp = (float4*)(p + (size_t)i * EMB);
    float4 a0 = ap[0], a1 = ap[1];
    float4 t0 = tp[0], t1 = tp[1];
    float inv = 1.0f / fmaxf(cnt[i], 1.0f);

    float h[EMB];
    h[0] = fmaxf(fmaf(a0.x, inv, t0.x), 0.f);
    h[1] = fmaxf(fmaf(a0.y, inv, t0.y), 0.f);
    h[2] = fmaxf(fmaf(a0.z, inv, t0.z), 0.f);
    h[3] = fmaxf(fmaf(a0.w, inv, t0.w), 0.f);
    h[4] = fmaxf(fmaf(a1.x, inv, t1.x), 0.f);
    h[5] = fmaxf(fmaf(a1.y, inv, t1.y), 0.f);
    h[6] = fmaxf(fmaf(a1.z, inv, t1.z), 0.f);
    h[7] = fmaxf(fmaf(a1.w, inv, t1.w), 0.f);

    float pe[EMB], te[EMB];
    #pragma unroll
    for (int e = 0; e < EMB; ++e) {
        float sp = 0.f, st = sb[e];
        #pragma unroll
        for (int k = 0; k < EMB; ++k) {
            sp = fmaf(h[k], sWl[e * EMB + k], sp);
            st = fmaf(h[k], sWr[e * EMB + k], st);
        }
        pe[e] = sp; te[e] = st;
    }

    pp[0] = make_float4(pe[0], pe[1], pe[2], pe[3]);
    pp[1] = make_float4(pe[4], pe[5], pe[6], pe[7]);
    tp[0] = make_float4(te[0], te[1], te[2], te[3]);
    tp[1] = make_float4(te[4], te[5], te[6], te[7]);
    ap[0] = make_float4(0.f, 0.f, 0.f, 0.f);
    ap[1] = make_float4(0.f, 0.f, 0.f, 0.f);
}

// ---------------- kernel 5: layer-2 finalize + log_softmax ----------------
__global__ __launch_bounds__(256) void k_out(
    const float* __restrict__ t,
    const float* __restrict__ agg,
    const float* __restrict__ cnt,
    float* __restrict__ out)
{
    int i = blockIdx.x * blockDim.x + threadIdx.x;
    if (i >= NN) return;

    const float4* ap = (const float4*)(agg + (size_t)i * EMB);
    const float4* tp = (const float4*)(t + (size_t)i * EMB);
    float4 a0 = ap[0], a1 = ap[1];
    float4 t0 = tp[0], t1 = tp[1];
    float inv = 1.0f / fmaxf(cnt[i], 1.0f);

    float z[EMB];
    z[0] = fmaf(a0.x, inv, t0.x);
    z[1] = fmaf(a0.y, inv, t0.y);
    z[2] = fmaf(a0.z, inv, t0.z);
    z[3] = fmaf(a0.w, inv, t0.w);
    z[4] = fmaf(a1.x, inv, t1.x);
    z[5] = fmaf(a1.y, inv, t1.y);
    z[6] = fmaf(a1.z, inv, t1.z);
    z[7] = fmaf(a1.w, inv, t1.w);

    float m = z[0];
    #pragma unroll
    for (int k = 1; k < EMB; ++k) m = fmaxf(m, z[k]);
    float s = 0.f;
    #pragma unroll
    for (int k = 0; k < EMB; ++k) s += expf(z[k] - m);
    float ls = m + logf(s);

    float4* op = (float4*)(out + (size_t)i * EMB);
    op[0] = make_float4(z[0] - ls, z[1] - ls, z[2] - ls, z[3] - ls);
    op[1] = make_float4(z[4] - ls, z[5] - ls, z[6] - ls, z[7] - ls);
}

extern "C" void kernel_launch(void* const* d_in, const int* in_sizes, int n_in,
                              void* d_out, int out_size, void* d_ws, size_t ws_size,
                              hipStream_t stream)
{
    const float* x   = (const float*)d_in[0];
    const int*   ei  = (const int*)d_in[1];    // [2, NE] flat
    const float* ew  = (const float*)d_in[2];
    const float* W1l = (const float*)d_in[3];
    const float* W1r = (const float*)d_in[4];
    const float* b1  = (const float*)d_in[5];
    const float* W3l = (const float*)d_in[6];
    const float* W3r = (const float*)d_in[7];
    const float* b3  = (const float*)d_in[8];
    float* out = (float*)d_out;

    const int* src = ei;
    const int* dst = ei + NE;

    // workspace layout (floats): p[NN*8] | t[NN*8] | agg[NN*8] | cnt[NN]
    float* p   = (float*)d_ws;
    float* t   = p + (size_t)NN * EMB;
    float* agg = t + (size_t)NN * EMB;
    float* cnt = agg + (size_t)NN * EMB;

    dim3 blk(256);
    dim3 gN((NN + 255) / 256);
    dim3 gE((NE + 255) / 256);

    k_init<<<gN, blk, 0, stream>>>(x, W1l, W1r, b1, p, t, agg, cnt);
    k_scatter<true><<<gE, blk, 0, stream>>>(src, dst, ew, p, agg, cnt);
    k_mid<<<gN, blk, 0, stream>>>(W3l, W3r, b3, p, t, agg, cnt);
    k_scatter<false><<<gE, blk, 0, stream>>>(src, dst, ew, p, agg, cnt);
    k_out<<<gN, blk, 0, stream>>>(t, agg, cnt, out);
}

// Round 2
// 576.157 us; speedup vs baseline: 4.7626x; 4.7626x over previous
//
#include <hip/hip_runtime.h>
#include <math.h>

#define NN 200000
#define NE 3200000
#define IN_DIM 16
#define EMB 8
#define NBLK ((NN + 255) / 256)   // 782

// ---------------- kernel 1: node init ----------------
// pA = x @ W1l^T (gathered later), t = x @ W1r^T + b1 (self term), deg = 0
__global__ __launch_bounds__(256) void k_init(
    const float* __restrict__ x,
    const float* __restrict__ W1l,   // [8][16]
    const float* __restrict__ W1r,   // [8][16]
    const float* __restrict__ b1,    // [8]
    float* __restrict__ pA, float* __restrict__ t,
    int* __restrict__ deg)
{
    __shared__ float sWl[EMB * IN_DIM];
    __shared__ float sWr[EMB * IN_DIM];
    __shared__ float sb[EMB];
    int tid = threadIdx.x;
    if (tid < EMB * IN_DIM) { sWl[tid] = W1l[tid]; sWr[tid] = W1r[tid]; }
    if (tid < EMB) sb[tid] = b1[tid];
    __syncthreads();

    int i = blockIdx.x * blockDim.x + tid;
    if (i >= NN) return;

    float xi[IN_DIM];
    const float4* xp = (const float4*)(x + (size_t)i * IN_DIM);
    #pragma unroll
    for (int q = 0; q < 4; ++q) {
        float4 v = xp[q];
        xi[4*q+0] = v.x; xi[4*q+1] = v.y; xi[4*q+2] = v.z; xi[4*q+3] = v.w;
    }

    float pe[EMB], te[EMB];
    #pragma unroll
    for (int e = 0; e < EMB; ++e) {
        float sp = 0.f, st = sb[e];
        #pragma unroll
        for (int k = 0; k < IN_DIM; ++k) {
            sp = fmaf(xi[k], sWl[e * IN_DIM + k], sp);
            st = fmaf(xi[k], sWr[e * IN_DIM + k], st);
        }
        pe[e] = sp; te[e] = st;
    }

    float4* pp = (float4*)(pA + (size_t)i * EMB);
    float4* tp = (float4*)(t + (size_t)i * EMB);
    pp[0] = make_float4(pe[0], pe[1], pe[2], pe[3]);
    pp[1] = make_float4(pe[4], pe[5], pe[6], pe[7]);
    tp[0] = make_float4(te[0], te[1], te[2], te[3]);
    tp[1] = make_float4(te[4], te[5], te[6], te[7]);
    deg[i] = 0;
}

// ---------------- kernel 2: degree histogram ----------------
__global__ __launch_bounds__(256) void k_hist(
    const int* __restrict__ dst, int* __restrict__ deg)
{
    int e = blockIdx.x * blockDim.x + threadIdx.x;
    if (e >= NE) return;
    atomicAdd(deg + dst[e], 1);
}

// ---------------- scan step 1: per-block sums ----------------
__global__ __launch_bounds__(256) void k_blocksum(
    const int* __restrict__ deg, int* __restrict__ partial)
{
    __shared__ int sh[256];
    int tid = threadIdx.x;
    int i = blockIdx.x * 256 + tid;
    sh[tid] = (i < NN) ? deg[i] : 0;
    __syncthreads();
    for (int s = 128; s > 0; s >>= 1) {
        if (tid < s) sh[tid] += sh[tid + s];
        __syncthreads();
    }
    if (tid == 0) partial[blockIdx.x] = sh[0];
}

// ---------------- scan step 2: exclusive scan of partials (single block) ----------------
__global__ __launch_bounds__(1024) void k_scanpartial(int* __restrict__ partial)
{
    __shared__ int sh[1024];
    int tid = threadIdx.x;
    int v = (tid < NBLK) ? partial[tid] : 0;
    sh[tid] = v;
    __syncthreads();
    for (int o = 1; o < 1024; o <<= 1) {
        int tv = (tid >= o) ? sh[tid - o] : 0;
        __syncthreads();
        sh[tid] += tv;
        __syncthreads();
    }
    if (tid < NBLK) partial[tid] = sh[tid] - v;   // exclusive
}

// ---------------- scan step 3: per-block exclusive scan + add base ----------------
__global__ __launch_bounds__(256) void k_scan3(
    const int* __restrict__ deg, const int* __restrict__ partial,
    int* __restrict__ off, int* __restrict__ cursor)
{
    __shared__ int sh[256];
    int tid = threadIdx.x;
    int i = blockIdx.x * 256 + tid;
    int v = (i < NN) ? deg[i] : 0;
    sh[tid] = v;
    __syncthreads();
    for (int o = 1; o < 256; o <<= 1) {
        int tv = (tid >= o) ? sh[tid - o] : 0;
        __syncthreads();
        sh[tid] += tv;
        __syncthreads();
    }
    int excl = partial[blockIdx.x] + sh[tid] - v;
    if (i < NN) {
        off[i] = excl;
        cursor[i] = excl;
        if (i == NN - 1) off[NN] = excl + v;
    }
}

// ---------------- kernel: place edges into CSR order ----------------
__global__ __launch_bounds__(256) void k_place(
    const int* __restrict__ src, const int* __restrict__ dst,
    const float* __restrict__ w,
    int* __restrict__ cursor, int2* __restrict__ sorted)
{
    int e = blockIdx.x * blockDim.x + threadIdx.x;
    if (e >= NE) return;
    int d = dst[e];
    int pos = atomicAdd(cursor + d, 1);
    int2 rec;
    rec.x = src[e];
    rec.y = __float_as_int(w[e]);
    sorted[pos] = rec;
}

// ---------------- kernel: layer-1 gather-aggregate + mid projection ----------------
// mean = (sum_j pA[src_j]*w_j)/max(deg,1); h = relu(mean + t);
// pB = h @ W3l^T; t <- h @ W3r^T + b3   (t row i only read/written by node i: safe in-place)
__global__ __launch_bounds__(256) void k_agg1(
    const int2* __restrict__ sorted, const int* __restrict__ off,
    const float* __restrict__ pA, float* __restrict__ t,
    const float* __restrict__ W3l, const float* __restrict__ W3r,
    const float* __restrict__ b3,
    float* __restrict__ pB)
{
    __shared__ float sWl[EMB * EMB];
    __shared__ float sWr[EMB * EMB];
    __shared__ float sb[EMB];
    int tid = threadIdx.x;
    if (tid < EMB * EMB) { sWl[tid] = W3l[tid]; sWr[tid] = W3r[tid]; }
    if (tid < EMB) sb[tid] = b3[tid];
    __syncthreads();

    int i = blockIdx.x * 256 + tid;
    if (i >= NN) return;

    int b = off[i], e = off[i + 1];
    float acc[EMB] = {0,0,0,0,0,0,0,0};
    for (int j = b; j < e; ++j) {
        int2 r = sorted[j];
        float w = __int_as_float(r.y);
        const float4* ps = (const float4*)(pA + (size_t)r.x * EMB);
        float4 v0 = ps[0], v1 = ps[1];
        acc[0] = fmaf(v0.x, w, acc[0]);
        acc[1] = fmaf(v0.y, w, acc[1]);
        acc[2] = fmaf(v0.z, w, acc[2]);
        acc[3] = fmaf(v0.w, w, acc[3]);
        acc[4] = fmaf(v1.x, w, acc[4]);
        acc[5] = fmaf(v1.y, w, acc[5]);
        acc[6] = fmaf(v1.z, w, acc[6]);
        acc[7] = fmaf(v1.w, w, acc[7]);
    }
    float inv = 1.0f / fmaxf((float)(e - b), 1.0f);

    float4* tp = (float4*)(t + (size_t)i * EMB);
    float4 t0 = tp[0], t1 = tp[1];
    float h[EMB];
    h[0] = fmaxf(fmaf(acc[0], inv, t0.x), 0.f);
    h[1] = fmaxf(fmaf(acc[1], inv, t0.y), 0.f);
    h[2] = fmaxf(fmaf(acc[2], inv, t0.z), 0.f);
    h[3] = fmaxf(fmaf(acc[3], inv, t0.w), 0.f);
    h[4] = fmaxf(fmaf(acc[4], inv, t1.x), 0.f);
    h[5] = fmaxf(fmaf(acc[5], inv, t1.y), 0.f);
    h[6] = fmaxf(fmaf(acc[6], inv, t1.z), 0.f);
    h[7] = fmaxf(fmaf(acc[7], inv, t1.w), 0.f);

    float pe[EMB], te[EMB];
    #pragma unroll
    for (int o = 0; o < EMB; ++o) {
        float sp = 0.f, st = sb[o];
        #pragma unroll
        for (int k = 0; k < EMB; ++k) {
            sp = fmaf(h[k], sWl[o * EMB + k], sp);
            st = fmaf(h[k], sWr[o * EMB + k], st);
        }
        pe[o] = sp; te[o] = st;
    }

    float4* pp = (float4*)(pB + (size_t)i * EMB);
    pp[0] = make_float4(pe[0], pe[1], pe[2], pe[3]);
    pp[1] = make_float4(pe[4], pe[5], pe[6], pe[7]);
    tp[0] = make_float4(te[0], te[1], te[2], te[3]);
    tp[1] = make_float4(te[4], te[5], te[6], te[7]);
}

// ---------------- kernel: layer-2 gather-aggregate + log_softmax ----------------
__global__ __launch_bounds__(256) void k_agg2(
    const int2* __restrict__ sorted, const int* __restrict__ off,
    const float* __restrict__ pB, const float* __restrict__ t,
    float* __restrict__ out)
{
    int i = blockIdx.x * 256 + threadIdx.x;
    if (i >= NN) return;

    int b = off[i], e = off[i + 1];
    float acc[EMB] = {0,0,0,0,0,0,0,0};
    for (int j = b; j < e; ++j) {
        int2 r = sorted[j];
        float w = __int_as_float(r.y);
        const float4* ps = (const float4*)(pB + (size_t)r.x * EMB);
        float4 v0 = ps[0], v1 = ps[1];
        acc[0] = fmaf(v0.x, w, acc[0]);
        acc[1] = fmaf(v0.y, w, acc[1]);
        acc[2] = fmaf(v0.z, w, acc[2]);
        acc[3] = fmaf(v0.w, w, acc[3]);
        acc[4] = fmaf(v1.x, w, acc[4]);
        acc[5] = fmaf(v1.y, w, acc[5]);
        acc[6] = fmaf(v1.z, w, acc[6]);
        acc[7] = fmaf(v1.w, w, acc[7]);
    }
    float inv = 1.0f / fmaxf((float)(e - b), 1.0f);

    const float4* tp = (const float4*)(t + (size_t)i * EMB);
    float4 t0 = tp[0], t1 = tp[1];
    float z[EMB];
    z[0] = fmaf(acc[0], inv, t0.x);
    z[1] = fmaf(acc[1], inv, t0.y);
    z[2] = fmaf(acc[2], inv, t0.z);
    z[3] = fmaf(acc[3], inv, t0.w);
    z[4] = fmaf(acc[4], inv, t1.x);
    z[5] = fmaf(acc[5], inv, t1.y);
    z[6] = fmaf(acc[6], inv, t1.z);
    z[7] = fmaf(acc[7], inv, t1.w);

    float m = z[0];
    #pragma unroll
    for (int k = 1; k < EMB; ++k) m = fmaxf(m, z[k]);
    float s = 0.f;
    #pragma unroll
    for (int k = 0; k < EMB; ++k) s += expf(z[k] - m);
    float ls = m + logf(s);

    float4* op = (float4*)(out + (size_t)i * EMB);
    op[0] = make_float4(z[0] - ls, z[1] - ls, z[2] - ls, z[3] - ls);
    op[1] = make_float4(z[4] - ls, z[5] - ls, z[6] - ls, z[7] - ls);
}

extern "C" void kernel_launch(void* const* d_in, const int* in_sizes, int n_in,
                              void* d_out, int out_size, void* d_ws, size_t ws_size,
                              hipStream_t stream)
{
    const float* x   = (const float*)d_in[0];
    const int*   ei  = (const int*)d_in[1];    // [2, NE] flat
    const float* ew  = (const float*)d_in[2];
    const float* W1l = (const float*)d_in[3];
    const float* W1r = (const float*)d_in[4];
    const float* b1  = (const float*)d_in[5];
    const float* W3l = (const float*)d_in[6];
    const float* W3r = (const float*)d_in[7];
    const float* b3  = (const float*)d_in[8];
    float* out = (float*)d_out;

    const int* src = ei;
    const int* dst = ei + NE;

    // workspace layout:
    // pA [NN*8 f] | pB [NN*8 f] | t [NN*8 f] | deg [NN i] | off [NN+1 i]
    // | cursor [NN i] | partial [NBLK i] | sorted [NE int2]
    char* w = (char*)d_ws;
    float* pA   = (float*)w;                 w += (size_t)NN * EMB * 4;
    float* pB   = (float*)w;                 w += (size_t)NN * EMB * 4;
    float* t    = (float*)w;                 w += (size_t)NN * EMB * 4;
    int*   deg  = (int*)w;                   w += (size_t)NN * 4;
    int*   off  = (int*)w;                   w += (size_t)(NN + 1) * 4;
    int*   cur  = (int*)w;                   w += (size_t)NN * 4;
    int*   part = (int*)w;                   w += (size_t)NBLK * 4;
    // align sorted to 8 bytes
    w = (char*)(((size_t)w + 7) & ~(size_t)7);
    int2*  sorted = (int2*)w;

    dim3 blk(256);
    dim3 gN(NBLK);
    dim3 gE((NE + 255) / 256);

    k_init<<<gN, blk, 0, stream>>>(x, W1l, W1r, b1, pA, t, deg);
    k_hist<<<gE, blk, 0, stream>>>(dst, deg);
    k_blocksum<<<gN, blk, 0, stream>>>(deg, part);
    k_scanpartial<<<1, 1024, 0, stream>>>(part);
    k_scan3<<<gN, blk, 0, stream>>>(deg, part, off, cur);
    k_place<<<gE, blk, 0, stream>>>(src, dst, ew, cur, sorted);
    k_agg1<<<gN, blk, 0, stream>>>(sorted, off, pA, t, W3l, W3r, b3, pB);
    k_agg2<<<gN, blk, 0, stream>>>(sorted, off, pB, t, out);
}

// Round 3
// 433.139 us; speedup vs baseline: 6.3352x; 1.3302x over previous
//
#include <hip/hip_runtime.h>
#include <math.h>

#define NN 200000
#define NE 3200000
#define IN_DIM 16
#define EMB 8
#define BK 256                            // nodes per bucket
#define NBUK ((NN + BK - 1) / BK)         // 782
#define NBLK ((NN + 255) / 256)           // 782
#define PLACE_BLOCKS 512
#define CHUNK ((NE + PLACE_BLOCKS - 1) / PLACE_BLOCKS)   // 6250

// ---------------- kernel 1: node init ----------------
// pA = x @ W1l^T (gathered later), t = x @ W1r^T + b1 (self term); zero bucket counts
__global__ __launch_bounds__(256) void k_init(
    const float* __restrict__ x,
    const float* __restrict__ W1l,   // [8][16]
    const float* __restrict__ W1r,   // [8][16]
    const float* __restrict__ b1,    // [8]
    float* __restrict__ pA, float* __restrict__ t,
    int* __restrict__ bcnt)
{
    __shared__ float sWl[EMB * IN_DIM];
    __shared__ float sWr[EMB * IN_DIM];
    __shared__ float sb[EMB];
    int tid = threadIdx.x;
    if (tid < EMB * IN_DIM) { sWl[tid] = W1l[tid]; sWr[tid] = W1r[tid]; }
    if (tid < EMB) sb[tid] = b1[tid];
    __syncthreads();

    int i = blockIdx.x * blockDim.x + tid;
    if (i < NBUK && blockIdx.x == 0) { /* covered below by gid check */ }
    int gid = i;
    if (gid < NBUK) bcnt[gid] = 0;
    if (i >= NN) return;

    float xi[IN_DIM];
    const float4* xp = (const float4*)(x + (size_t)i * IN_DIM);
    #pragma unroll
    for (int q = 0; q < 4; ++q) {
        float4 v = xp[q];
        xi[4*q+0] = v.x; xi[4*q+1] = v.y; xi[4*q+2] = v.z; xi[4*q+3] = v.w;
    }

    float pe[EMB], te[EMB];
    #pragma unroll
    for (int e = 0; e < EMB; ++e) {
        float sp = 0.f, st = sb[e];
        #pragma unroll
        for (int k = 0; k < IN_DIM; ++k) {
            sp = fmaf(xi[k], sWl[e * IN_DIM + k], sp);
            st = fmaf(xi[k], sWr[e * IN_DIM + k], st);
        }
        pe[e] = sp; te[e] = st;
    }

    float4* pp = (float4*)(pA + (size_t)i * EMB);
    float4* tp = (float4*)(t + (size_t)i * EMB);
    pp[0] = make_float4(pe[0], pe[1], pe[2], pe[3]);
    pp[1] = make_float4(pe[4], pe[5], pe[6], pe[7]);
    tp[0] = make_float4(te[0], te[1], te[2], te[3]);
    tp[1] = make_float4(te[4], te[5], te[6], te[7]);
}

// ---------------- kernel 2: bucket histogram (LDS-staged) ----------------
__global__ __launch_bounds__(256) void k_bhist(
    const int* __restrict__ dst, int* __restrict__ bcnt)
{
    __shared__ int h[NBUK];
    int tid = threadIdx.x;
    for (int i = tid; i < NBUK; i += 256) h[i] = 0;
    __syncthreads();
    int stride = gridDim.x * 256;
    for (int e = blockIdx.x * 256 + tid; e < NE; e += stride)
        atomicAdd(&h[dst[e] >> 8], 1);
    __syncthreads();
    for (int i = tid; i < NBUK; i += 256) {
        int v = h[i];
        if (v) atomicAdd(bcnt + i, v);
    }
}

// ---------------- kernel 3: scan bucket counts (1 block) ----------------
__global__ __launch_bounds__(1024) void k_bscan(
    const int* __restrict__ bcnt, int* __restrict__ bbase, int* __restrict__ bcur)
{
    __shared__ int sh[1024];
    int tid = threadIdx.x;
    int v = (tid < NBUK) ? bcnt[tid] : 0;
    sh[tid] = v;
    __syncthreads();
    for (int o = 1; o < 1024; o <<= 1) {
        int tv = (tid >= o) ? sh[tid - o] : 0;
        __syncthreads();
        sh[tid] += tv;
        __syncthreads();
    }
    if (tid < NBUK) {
        int excl = sh[tid] - v;
        bbase[tid] = excl;
        bcur[tid] = excl;
        if (tid == NBUK - 1) bbase[NBUK] = excl + v;
    }
}

// ---------------- kernel 4: place edges into bucket runs ----------------
// Per block: LDS histogram of its chunk -> reserve one run per bucket via one
// global atomic -> rank edges via LDS cursor -> write records block-contiguously.
__global__ __launch_bounds__(256) void k_bplace(
    const int* __restrict__ src, const int* __restrict__ dst,
    const float* __restrict__ w,
    int* __restrict__ bcur, int2* __restrict__ recs)
{
    __shared__ int h[NBUK];     // pass A: counts; pass B: rank cursor
    __shared__ int base[NBUK];  // global run base for this block
    int tid = threadIdx.x;
    for (int i = tid; i < NBUK; i += 256) h[i] = 0;
    __syncthreads();

    long e0 = (long)blockIdx.x * CHUNK;
    long e1 = e0 + CHUNK; if (e1 > NE) e1 = NE;

    for (long e = e0 + tid; e < e1; e += 256)
        atomicAdd(&h[dst[e] >> 8], 1);
    __syncthreads();

    for (int i = tid; i < NBUK; i += 256) {
        int c = h[i];
        base[i] = c ? atomicAdd(bcur + i, c) : 0;
        h[i] = 0;
    }
    __syncthreads();

    for (long e = e0 + tid; e < e1; e += 256) {
        int d = dst[e];
        int b = d >> 8;
        int r = atomicAdd(&h[b], 1);
        int2 rec;
        rec.x = src[e] | ((d & (BK - 1)) << 18);
        rec.y = __float_as_int(w[e]);
        recs[base[b] + r] = rec;
    }
}

// ---------------- kernel 5: layer-1 bucket aggregate + mid projection ----------------
// One block per 256-node bucket. LDS accumulate (stride-9 pad), then
// h = relu(mean + t); pB = h@W3l^T; t <- h@W3r^T + b3.
__global__ __launch_bounds__(256) void k_agg1(
    const int2* __restrict__ recs, const int* __restrict__ bbase,
    const float* __restrict__ pA, float* __restrict__ t,
    const float* __restrict__ W3l, const float* __restrict__ W3r,
    const float* __restrict__ b3,
    float* __restrict__ pB)
{
    __shared__ float sWl[EMB * EMB];
    __shared__ float sWr[EMB * EMB];
    __shared__ float sb[EMB];
    __shared__ float sagg[BK * 9];
    __shared__ int scnt[BK];
    int tid = threadIdx.x;
    if (tid < EMB * EMB) { sWl[tid] = W3l[tid]; sWr[tid] = W3r[tid]; }
    if (tid < EMB) sb[tid] = b3[tid];
    for (int i = tid; i < BK * 9; i += 256) sagg[i] = 0.f;
    scnt[tid] = 0;
    __syncthreads();

    int b = blockIdx.x;
    int rb = bbase[b], re = bbase[b + 1];
    for (int j = rb + tid; j < re; j += 256) {
        int2 r = recs[j];
        unsigned hi = (unsigned)r.x;
        int s  = hi & 0x3FFFF;
        int dl = hi >> 18;
        float w = __int_as_float(r.y);
        const float4* ps = (const float4*)(pA + (size_t)s * EMB);
        float4 v0 = ps[0], v1 = ps[1];
        float* ag = &sagg[dl * 9];
        atomicAdd(ag + 0, v0.x * w);
        atomicAdd(ag + 1, v0.y * w);
        atomicAdd(ag + 2, v0.z * w);
        atomicAdd(ag + 3, v0.w * w);
        atomicAdd(ag + 4, v1.x * w);
        atomicAdd(ag + 5, v1.y * w);
        atomicAdd(ag + 6, v1.z * w);
        atomicAdd(ag + 7, v1.w * w);
        atomicAdd(&scnt[dl], 1);
    }
    __syncthreads();

    int i = b * BK + tid;
    if (i >= NN) return;

    float inv = 1.0f / fmaxf((float)scnt[tid], 1.0f);
    float* ag = &sagg[tid * 9];
    float4* tp = (float4*)(t + (size_t)i * EMB);
    float4 t0 = tp[0], t1 = tp[1];

    float h[EMB];
    h[0] = fmaxf(fmaf(ag[0], inv, t0.x), 0.f);
    h[1] = fmaxf(fmaf(ag[1], inv, t0.y), 0.f);
    h[2] = fmaxf(fmaf(ag[2], inv, t0.z), 0.f);
    h[3] = fmaxf(fmaf(ag[3], inv, t0.w), 0.f);
    h[4] = fmaxf(fmaf(ag[4], inv, t1.x), 0.f);
    h[5] = fmaxf(fmaf(ag[5], inv, t1.y), 0.f);
    h[6] = fmaxf(fmaf(ag[6], inv, t1.z), 0.f);
    h[7] = fmaxf(fmaf(ag[7], inv, t1.w), 0.f);

    float pe[EMB], te[EMB];
    #pragma unroll
    for (int o = 0; o < EMB; ++o) {
        float sp = 0.f, st = sb[o];
        #pragma unroll
        for (int k = 0; k < EMB; ++k) {
            sp = fmaf(h[k], sWl[o * EMB + k], sp);
            st = fmaf(h[k], sWr[o * EMB + k], st);
        }
        pe[o] = sp; te[o] = st;
    }

    float4* pp = (float4*)(pB + (size_t)i * EMB);
    pp[0] = make_float4(pe[0], pe[1], pe[2], pe[3]);
    pp[1] = make_float4(pe[4], pe[5], pe[6], pe[7]);
    tp[0] = make_float4(te[0], te[1], te[2], te[3]);
    tp[1] = make_float4(te[4], te[5], te[6], te[7]);
}

// ---------------- kernel 6: layer-2 bucket aggregate + log_softmax ----------------
__global__ __launch_bounds__(256) void k_agg2(
    const int2* __restrict__ recs, const int* __restrict__ bbase,
    const float* __restrict__ pB, const float* __restrict__ t,
    float* __restrict__ out)
{
    __shared__ float sagg[BK * 9];
    __shared__ int scnt[BK];
    int tid = threadIdx.x;
    for (int i = tid; i < BK * 9; i += 256) sagg[i] = 0.f;
    scnt[tid] = 0;
    __syncthreads();

    int b = blockIdx.x;
    int rb = bbase[b], re = bbase[b + 1];
    for (int j = rb + tid; j < re; j += 256) {
        int2 r = recs[j];
        unsigned hi = (unsigned)r.x;
        int s  = hi & 0x3FFFF;
        int dl = hi >> 18;
        float w = __int_as_float(r.y);
        const float4* ps = (const float4*)(pB + (size_t)s * EMB);
        float4 v0 = ps[0], v1 = ps[1];
        float* ag = &sagg[dl * 9];
        atomicAdd(ag + 0, v0.x * w);
        atomicAdd(ag + 1, v0.y * w);
        atomicAdd(ag + 2, v0.z * w);
        atomicAdd(ag + 3, v0.w * w);
        atomicAdd(ag + 4, v1.x * w);
        atomicAdd(ag + 5, v1.y * w);
        atomicAdd(ag + 6, v1.z * w);
        atomicAdd(ag + 7, v1.w * w);
        atomicAdd(&scnt[dl], 1);
    }
    __syncthreads();

    int i = b * BK + tid;
    if (i >= NN) return;

    float inv = 1.0f / fmaxf((float)scnt[tid], 1.0f);
    float* ag = &sagg[tid * 9];
    const float4* tp = (const float4*)(t + (size_t)i * EMB);
    float4 t0 = tp[0], t1 = tp[1];

    float z[EMB];
    z[0] = fmaf(ag[0], inv, t0.x);
    z[1] = fmaf(ag[1], inv, t0.y);
    z[2] = fmaf(ag[2], inv, t0.z);
    z[3] = fmaf(ag[3], inv, t0.w);
    z[4] = fmaf(ag[4], inv, t1.x);
    z[5] = fmaf(ag[5], inv, t1.y);
    z[6] = fmaf(ag[6], inv, t1.z);
    z[7] = fmaf(ag[7], inv, t1.w);

    float m = z[0];
    #pragma unroll
    for (int k = 1; k < EMB; ++k) m = fmaxf(m, z[k]);
    float s = 0.f;
    #pragma unroll
    for (int k = 0; k < EMB; ++k) s += expf(z[k] - m);
    float ls = m + logf(s);

    float4* op = (float4*)(out + (size_t)i * EMB);
    op[0] = make_float4(z[0] - ls, z[1] - ls, z[2] - ls, z[3] - ls);
    op[1] = make_float4(z[4] - ls, z[5] - ls, z[6] - ls, z[7] - ls);
}

extern "C" void kernel_launch(void* const* d_in, const int* in_sizes, int n_in,
                              void* d_out, int out_size, void* d_ws, size_t ws_size,
                              hipStream_t stream)
{
    const float* x   = (const float*)d_in[0];
    const int*   ei  = (const int*)d_in[1];    // [2, NE] flat
    const float* ew  = (const float*)d_in[2];
    const float* W1l = (const float*)d_in[3];
    const float* W1r = (const float*)d_in[4];
    const float* b1  = (const float*)d_in[5];
    const float* W3l = (const float*)d_in[6];
    const float* W3r = (const float*)d_in[7];
    const float* b3  = (const float*)d_in[8];
    float* out = (float*)d_out;

    const int* src = ei;
    const int* dst = ei + NE;

    // workspace: pA [NN*8 f] | pB [NN*8 f] | t [NN*8 f] | bcnt [NBUK i]
    // | bbase [NBUK+1 i] | bcur [NBUK i] | recs [NE int2]
    char* w = (char*)d_ws;
    float* pA    = (float*)w;  w += (size_t)NN * EMB * 4;
    float* pB    = (float*)w;  w += (size_t)NN * EMB * 4;
    float* t     = (float*)w;  w += (size_t)NN * EMB * 4;
    int*   bcnt  = (int*)w;    w += (size_t)NBUK * 4;
    int*   bbase = (int*)w;    w += (size_t)(NBUK + 1) * 4;
    int*   bcur  = (int*)w;    w += (size_t)NBUK * 4;
    w = (char*)(((size_t)w + 7) & ~(size_t)7);
    int2*  recs  = (int2*)w;

    dim3 blk(256);

    k_init<<<dim3(NBLK), blk, 0, stream>>>(x, W1l, W1r, b1, pA, t, bcnt);
    k_bhist<<<dim3(PLACE_BLOCKS), blk, 0, stream>>>(dst, bcnt);
    k_bscan<<<dim3(1), dim3(1024), 0, stream>>>(bcnt, bbase, bcur);
    k_bplace<<<dim3(PLACE_BLOCKS), blk, 0, stream>>>(src, dst, ew, bcur, recs);
    k_agg1<<<dim3(NBUK), blk, 0, stream>>>(recs, bbase, pA, t, W3l, W3r, b3, pB);
    k_agg2<<<dim3(NBUK), blk, 0, stream>>>(recs, bbase, pB, t, out);
}